// Round 6
// baseline (323.946 us; speedup 1.0000x reference)
//
#include <hip/hip_runtime.h>
#include <stdint.h>

// GAT encoder, 2 layers, FULLY FUSED single kernel. B=128, K=512, Fin=224, H1=64, H2=32.
// One workgroup (1024 thr, 16 waves) per batch; ALL intermediates in a 144KB LDS arena
// (Wh frag-blocked, h1 stride-72, W1F/W2F blocked) + adjacency bits in 8 VGPRs/thread.
// Zero workspace use, zero inter-kernel deps, 5 barriers total.
// Softmax: att = exp(e-8)*mask / sum(exp(e-8)*mask) (exact; logits bounded ~+-7)

#define K_   512
#define FIN  224
#define H1   64
#define H2   32

typedef float    f32x4 __attribute__((ext_vector_type(4)));
typedef short    s16x8 __attribute__((ext_vector_type(8)));
typedef unsigned short u16;

__device__ __forceinline__ u16 f2bf(float f){              // RNE float->bf16
  uint32_t u = __float_as_uint(f);
  u += 0x7FFFu + ((u >> 16) & 1u);
  return (u16)(u >> 16);
}
__device__ __forceinline__ float bf2f(u16 h){ return __uint_as_float(((uint32_t)h) << 16); }

// fragment-blocked: elem (o,k) -> tile(k/32, o/16)*512 + ((o&15) + 16*((k&31)/8))*8 + (k&7)
__device__ __forceinline__ int fragoff(int o, int k, int NO){
  return (((k >> 5) * (NO >> 4) + (o >> 4)) << 9) + (((o & 15) + (((k & 31) >> 3) << 4)) << 3) + (k & 7);
}

// LDS arena byte offsets (total 147456 B = 144 KB):
//  [0,      65536)  WhS  : layer-1 Wh frag-blocked (512x64 bf16); reused as Wh2S (512x32) in layer 2
//  [65536, 139264)  region R:
//        phase A/B:  bits_tmp u32[16][512] @ +0 (32KB), W1F u16 blocked @ +32768 (28KB)
//        phase C..:  h1S u16[512][72] (73728 B, stride-72 padded)
//  [139264,143360)  W2F  : W2 frag-blocked (64x32 bf16, 4KB)
//  [143360,145408)  fs_s : float[512]
//  [145408,147456)  fd_s : float[512]

__global__ __launch_bounds__(1024, 4) void k_gat(const float* __restrict__ x, const int* __restrict__ adj,
                                                 const float* __restrict__ W1, const float* __restrict__ a1,
                                                 const float* __restrict__ W2, const float* __restrict__ a2,
                                                 float* __restrict__ out){
  __shared__ __align__(16) char arena[147456];
  u16*      WhS      = (u16*)     (arena);
  uint32_t* bits_tmp = (uint32_t*)(arena + 65536);
  u16*      W1F      = (u16*)     (arena + 98304);
  u16*      h1S      = (u16*)     (arena + 65536);
  u16*      W2F      = (u16*)     (arena + 139264);
  float*    fs_s     = (float*)   (arena + 143360);
  float*    fd_s     = (float*)   (arena + 145408);

  const int tid = threadIdx.x;
  const int w = tid >> 6, lane = tid & 63;
  const int g = lane >> 4, lr = lane & 15;
  const int b = blockIdx.x;

  // ---------------- phase A: W1F, W2F blocked; adj -> bits_tmp ----------------
  for (int e = tid; e < FIN * H1; e += 1024){
    const int k = e >> 6, o = e & 63;
    W1F[fragoff(o, k, H1)] = f2bf(W1[e]);
  }
#pragma unroll
  for (int p = 0; p < 2; ++p){
    const int e = tid + p * 1024;           // 2048 = H1*H2
    const int k = e >> 5, o = e & 31;
    W2F[fragoff(o, k, H2)] = f2bf(W2[e]);
  }
  {
    const int4* ap = reinterpret_cast<const int4*>(adj) + (size_t)b * 65536;
#pragma unroll 4
    for (int it = 0; it < 64; ++it){
      const int q = it * 1024 + tid;        // row = q>>7, j-quad = q&127
      int4 v = ap[q];
      uint32_t nib = (v.x != 0 ? 1u : 0u) | (v.y != 0 ? 2u : 0u) | (v.z != 0 ? 4u : 0u) | (v.w != 0 ? 8u : 0u);
      uint32_t val = nib << ((q & 7) * 4);
      val |= __shfl_xor(val, 1);
      val |= __shfl_xor(val, 2);
      val |= __shfl_xor(val, 4);
      if ((tid & 7) == 0)
        bits_tmp[((q & 127) >> 3) * K_ + (q >> 7)] = val;   // [st][row]
    }
  }
  __syncthreads();

  // ---------------- phase B: gemm1 (512 rows) -> WhS (blocked) + fs/fd ----------------
  {
    f32x4 acc[2][4];
#pragma unroll
    for (int h = 0; h < 2; ++h)
#pragma unroll
      for (int c = 0; c < 4; ++c) acc[h][c] = (f32x4){0.f,0.f,0.f,0.f};

    for (int s = 0; s < FIN / 32; ++s){
      s16x8 af[2];
#pragma unroll
      for (int h = 0; h < 2; ++h){
        const float* xr = x + ((size_t)b * K_ + 32 * w + 16 * h + lr) * FIN + s * 32 + 8 * g;
        float4 v0 = *(const float4*)xr;
        float4 v1 = *(const float4*)(xr + 4);
        af[h][0]=(short)f2bf(v0.x); af[h][1]=(short)f2bf(v0.y); af[h][2]=(short)f2bf(v0.z); af[h][3]=(short)f2bf(v0.w);
        af[h][4]=(short)f2bf(v1.x); af[h][5]=(short)f2bf(v1.y); af[h][6]=(short)f2bf(v1.z); af[h][7]=(short)f2bf(v1.w);
      }
#pragma unroll
      for (int c = 0; c < 4; ++c){
        const s16x8 bf = *(const s16x8*)&W1F[((s * 4 + c) << 9) + lane * 8];
#pragma unroll
        for (int h = 0; h < 2; ++h)
          acc[h][c] = __builtin_amdgcn_mfma_f32_16x16x32_bf16(af[h], bf, acc[h][c], 0, 0, 0);
      }
    }
    float fsp[2][4] = {{0}}, fdp[2][4] = {{0}};
#pragma unroll
    for (int h = 0; h < 2; ++h)
#pragma unroll
      for (int c = 0; c < 4; ++c){
        const int o = 16 * c + lr;
        const float as = a1[o], ad = a1[H1 + o];
#pragma unroll
        for (int r = 0; r < 4; ++r){ fsp[h][r] += acc[h][c][r] * as; fdp[h][r] += acc[h][c][r] * ad; }
        uint2 pk;
        pk.x = (uint32_t)f2bf(acc[h][c][0]) | ((uint32_t)f2bf(acc[h][c][1]) << 16);
        pk.y = (uint32_t)f2bf(acc[h][c][2]) | ((uint32_t)f2bf(acc[h][c][3]) << 16);
        const int off = ((w * 4 + c) << 9) + ((lr + 16 * (2 * h + (g >> 1))) << 3) + 4 * (g & 1);
        *(uint2*)&WhS[off] = pk;
      }
#pragma unroll
    for (int m = 1; m < 16; m <<= 1)
#pragma unroll
      for (int h = 0; h < 2; ++h)
#pragma unroll
        for (int r = 0; r < 4; ++r){ fsp[h][r] += __shfl_xor(fsp[h][r], m); fdp[h][r] += __shfl_xor(fdp[h][r], m); }
    if (lr == 0){
#pragma unroll
      for (int h = 0; h < 2; ++h)
#pragma unroll
        for (int r = 0; r < 4; ++r){
          const int row = 32 * w + 16 * h + 4 * g + r;
          fs_s[row] = fsp[h][r]; fd_s[row] = fdp[h][r];
        }
    }
  }

  // ---------------- phase B2: bits -> 8 VGPRs/thread ----------------
  uint32_t bw[2][4] = {{0,0,0,0},{0,0,0,0}};
#pragma unroll
  for (int h = 0; h < 2; ++h){
    const int row = 32 * w + 16 * h + lr;
#pragma unroll
    for (int st = 0; st < 16; ++st){
      const uint32_t byte = (bits_tmp[st * K_ + row] >> (8 * g)) & 0xFFu;
      bw[h][st >> 2] |= byte << (8 * (st & 3));
    }
  }
  __syncthreads();

  // ---------------- phase C: attn1 -> h1S (stride-72, elu'd, bf16) ----------------
  {
    f32x4 acc[2][4];
#pragma unroll
    for (int h = 0; h < 2; ++h)
#pragma unroll
      for (int c = 0; c < 4; ++c) acc[h][c] = (f32x4){0.f,0.f,0.f,0.f};
    float lsum[2] = {0.f, 0.f};
    const float fsr[2] = { fs_s[32 * w + lr], fs_s[32 * w + 16 + lr] };

    for (int st = 0; st < 16; ++st){
      const int j0 = 32 * st + 8 * g;
      float4 fd0 = *(const float4*)&fd_s[j0];
      float4 fd1 = *(const float4*)&fd_s[j0 + 4];
      const float pv[8] = { fd0.x, fd0.y, fd0.z, fd0.w, fd1.x, fd1.y, fd1.z, fd1.w };
      s16x8 bp[2];
#pragma unroll
      for (int h = 0; h < 2; ++h){
        const uint32_t byte = (bw[h][st >> 2] >> (8 * (st & 3))) & 0xFFu;
        float lacc = 0.f;
#pragma unroll
        for (int e = 0; e < 8; ++e){
          float sc = fsr[h] + pv[e];
          sc = fmaxf(sc, 0.2f * sc);                 // leaky_relu
          float pe = __expf(sc - 8.0f);
          pe = ((byte >> e) & 1u) ? pe : 0.f;
          u16 hh = f2bf(pe);
          bp[h][e] = (short)hh;
          lacc += bf2f(hh);
        }
        lsum[h] += lacc;
      }
#pragma unroll
      for (int c = 0; c < 4; ++c){
        const s16x8 aw = *(const s16x8*)&WhS[((st * 4 + c) << 9) + lane * 8];
#pragma unroll
        for (int h = 0; h < 2; ++h)
          acc[h][c] = __builtin_amdgcn_mfma_f32_16x16x32_bf16(aw, bp[h], acc[h][c], 0, 0, 0);
      }
    }
    float inv[2];
#pragma unroll
    for (int h = 0; h < 2; ++h){
      lsum[h] += __shfl_xor(lsum[h], 16);
      lsum[h] += __shfl_xor(lsum[h], 32);
      inv[h] = 1.0f / lsum[h];
    }
    // write h1 = elu(acc/lsum) into h1S (overwrites bits_tmp/W1F; reads of those fenced above)
#pragma unroll
    for (int h = 0; h < 2; ++h){
      const int irow = 32 * w + 16 * h + lr;
#pragma unroll
      for (int c = 0; c < 4; ++c){
        float v[4];
#pragma unroll
        for (int r = 0; r < 4; ++r){
          float t = acc[h][c][r] * inv[h];
          v[r] = t > 0.f ? t : (__expf(t) - 1.0f);   // elu
        }
        uint2 pk;
        pk.x = (uint32_t)f2bf(v[0]) | ((uint32_t)f2bf(v[1]) << 16);
        pk.y = (uint32_t)f2bf(v[2]) | ((uint32_t)f2bf(v[3]) << 16);
        *(uint2*)&h1S[irow * 72 + 16 * c + 4 * g] = pk;
      }
    }
  }
  __syncthreads();

  // ---------------- phase D: gemm2 (512 rows) -> Wh2S (reuses WhS) + fs/fd (layer 2) ----------------
  {
    f32x4 acc[2][2];
#pragma unroll
    for (int h = 0; h < 2; ++h)
#pragma unroll
      for (int c = 0; c < 2; ++c) acc[h][c] = (f32x4){0.f,0.f,0.f,0.f};

#pragma unroll
    for (int s = 0; s < H1 / 32; ++s){
      s16x8 af[2];
#pragma unroll
      for (int h = 0; h < 2; ++h)
        af[h] = *(const s16x8*)&h1S[(32 * w + 16 * h + lr) * 72 + s * 32 + 8 * g];
#pragma unroll
      for (int c = 0; c < 2; ++c){
        const s16x8 bf = *(const s16x8*)&W2F[((s * 2 + c) << 9) + lane * 8];
#pragma unroll
        for (int h = 0; h < 2; ++h)
          acc[h][c] = __builtin_amdgcn_mfma_f32_16x16x32_bf16(af[h], bf, acc[h][c], 0, 0, 0);
      }
    }
    float fsp[2][4] = {{0}}, fdp[2][4] = {{0}};
#pragma unroll
    for (int h = 0; h < 2; ++h)
#pragma unroll
      for (int c = 0; c < 2; ++c){
        const int o = 16 * c + lr;
        const float as = a2[o], ad = a2[H2 + o];
#pragma unroll
        for (int r = 0; r < 4; ++r){ fsp[h][r] += acc[h][c][r] * as; fdp[h][r] += acc[h][c][r] * ad; }
        uint2 pk;
        pk.x = (uint32_t)f2bf(acc[h][c][0]) | ((uint32_t)f2bf(acc[h][c][1]) << 16);
        pk.y = (uint32_t)f2bf(acc[h][c][2]) | ((uint32_t)f2bf(acc[h][c][3]) << 16);
        const int off = ((w * 2 + c) << 9) + ((lr + 16 * (2 * h + (g >> 1))) << 3) + 4 * (g & 1);
        *(uint2*)&WhS[off] = pk;                     // Wh2S
      }
#pragma unroll
    for (int m = 1; m < 16; m <<= 1)
#pragma unroll
      for (int h = 0; h < 2; ++h)
#pragma unroll
        for (int r = 0; r < 4; ++r){ fsp[h][r] += __shfl_xor(fsp[h][r], m); fdp[h][r] += __shfl_xor(fdp[h][r], m); }
    if (lr == 0){
#pragma unroll
      for (int h = 0; h < 2; ++h)
#pragma unroll
        for (int r = 0; r < 4; ++r){
          const int row = 32 * w + 16 * h + 4 * g + r;
          fs_s[row] = fsp[h][r]; fd_s[row] = fdp[h][r];
        }
    }
  }
  __syncthreads();

  // ---------------- phase E: attn2 -> out (f32) ----------------
  {
    f32x4 acc[2][2];
#pragma unroll
    for (int h = 0; h < 2; ++h)
#pragma unroll
      for (int c = 0; c < 2; ++c) acc[h][c] = (f32x4){0.f,0.f,0.f,0.f};
    float lsum[2] = {0.f, 0.f};
    const float fsr[2] = { fs_s[32 * w + lr], fs_s[32 * w + 16 + lr] };

    for (int st = 0; st < 16; ++st){
      const int j0 = 32 * st + 8 * g;
      float4 fd0 = *(const float4*)&fd_s[j0];
      float4 fd1 = *(const float4*)&fd_s[j0 + 4];
      const float pv[8] = { fd0.x, fd0.y, fd0.z, fd0.w, fd1.x, fd1.y, fd1.z, fd1.w };
      s16x8 bp[2];
#pragma unroll
      for (int h = 0; h < 2; ++h){
        const uint32_t byte = (bw[h][st >> 2] >> (8 * (st & 3))) & 0xFFu;
        float lacc = 0.f;
#pragma unroll
        for (int e = 0; e < 8; ++e){
          float sc = fsr[h] + pv[e];
          sc = fmaxf(sc, 0.2f * sc);
          float pe = __expf(sc - 8.0f);
          pe = ((byte >> e) & 1u) ? pe : 0.f;
          u16 hh = f2bf(pe);
          bp[h][e] = (short)hh;
          lacc += bf2f(hh);
        }
        lsum[h] += lacc;
      }
#pragma unroll
      for (int c = 0; c < 2; ++c){
        const s16x8 aw = *(const s16x8*)&WhS[((st * 2 + c) << 9) + lane * 8];
#pragma unroll
        for (int h = 0; h < 2; ++h)
          acc[h][c] = __builtin_amdgcn_mfma_f32_16x16x32_bf16(aw, bp[h], acc[h][c], 0, 0, 0);
      }
    }
    float inv[2];
#pragma unroll
    for (int h = 0; h < 2; ++h){
      lsum[h] += __shfl_xor(lsum[h], 16);
      lsum[h] += __shfl_xor(lsum[h], 32);
      inv[h] = 1.0f / lsum[h];
    }
#pragma unroll
    for (int h = 0; h < 2; ++h){
      const int irow = 32 * w + 16 * h + lr;
#pragma unroll
      for (int c = 0; c < 2; ++c){
        float v[4];
#pragma unroll
        for (int r = 0; r < 4; ++r){
          float t = acc[h][c][r] * inv[h];
          v[r] = t > 0.f ? t : (__expf(t) - 1.0f);
        }
        *(float4*)&out[((size_t)b * K_ + irow) * H2 + 16 * c + 4 * g] = (float4){v[0], v[1], v[2], v[3]};
      }
    }
  }
}

extern "C" void kernel_launch(void* const* d_in, const int* in_sizes, int n_in,
                              void* d_out, int out_size, void* d_ws, size_t ws_size,
                              hipStream_t stream){
  const float* x   = (const float*)d_in[0];
  const int*   adj = (const int*)  d_in[1];
  const float* W1  = (const float*)d_in[2];
  const float* a1  = (const float*)d_in[3];
  const float* W2  = (const float*)d_in[4];
  const float* a2  = (const float*)d_in[5];
  float* out = (float*)d_out;
  (void)d_ws; (void)ws_size;

  k_gat<<<dim3(128), dim3(1024), 0, stream>>>(x, adj, W1, a1, W2, a2, out);
}